// Round 1
// baseline (498.828 us; speedup 1.0000x reference)
//
#include <hip/hip_runtime.h>
#include <hip/hip_bf16.h>
#include <stdint.h>

typedef unsigned short u16;
typedef short bf16x8 __attribute__((ext_vector_type(8)));
typedef float f32x4 __attribute__((ext_vector_type(4)));

#define DEV __device__ __forceinline__

DEV u16 f2bf(float f) {
  union { float f; uint32_t u; } v; v.f = f;
  uint32_t u = v.u;
  return (u16)((u + 0x7FFFu + ((u >> 16) & 1u)) >> 16);
}
DEV float bf2f(u16 h) {
  union { uint32_t u; float f; } v; v.u = ((uint32_t)h) << 16;
  return v.f;
}

#define GLL(gp, lp) __builtin_amdgcn_global_load_lds(\
    (const __attribute__((address_space(1))) unsigned int*)(gp), \
    (__attribute__((address_space(3))) unsigned int*)(lp), 16, 0, 0)

// ---------------- prep kernels ----------------
__global__ void prep_x(const float* __restrict__ x, u16* __restrict__ xh, u16* __restrict__ xl) {
  int i = blockIdx.x * 256 + threadIdx.x;      // 2M threads, 4 elems each
  float4 v = ((const float4*)x)[i];
  ushort4 h, lo;
  h.x = f2bf(v.x); h.y = f2bf(v.y); h.z = f2bf(v.z); h.w = f2bf(v.w);
  lo.x = f2bf(v.x - bf2f(h.x)); lo.y = f2bf(v.y - bf2f(h.y));
  lo.z = f2bf(v.z - bf2f(h.z)); lo.w = f2bf(v.w - bf2f(h.w));
  ((ushort4*)xh)[i] = h;
  ((ushort4*)xl)[i] = lo;
}

__global__ void prep_w(const float* __restrict__ wq, const float* __restrict__ wk,
                       const float* __restrict__ wv, const float* __restrict__ wo,
                       u16* __restrict__ wqkh, u16* __restrict__ wqkl,
                       u16* __restrict__ wvb, u16* __restrict__ wob) {
  int i = blockIdx.x * 256 + threadIdx.x;      // 1M threads, 4 elems each
  int seg = i >> 18;
  int j = i & ((1 << 18) - 1);
  const float* src = (seg == 0) ? wq : (seg == 1) ? wk : (seg == 2) ? wv : wo;
  float4 v = ((const float4*)src)[j];
  ushort4 h;
  h.x = f2bf(v.x); h.y = f2bf(v.y); h.z = f2bf(v.z); h.w = f2bf(v.w);
  if (seg < 2) {
    ushort4 lo;
    lo.x = f2bf(v.x - bf2f(h.x)); lo.y = f2bf(v.y - bf2f(h.y));
    lo.z = f2bf(v.z - bf2f(h.z)); lo.w = f2bf(v.w - bf2f(h.w));
    ((ushort4*)wqkh)[i] = h;
    ((ushort4*)wqkl)[i] = lo;
  } else if (seg == 2) {
    ((ushort4*)wvb)[j] = h;
  } else {
    ((ushort4*)wob)[j] = h;
  }
}

// ---------------- fused QKV projection GEMM ----------------
// C[8192][3072]: cols 0..2047 -> QK (split hi/lo out), cols 2048..3071 -> V (bf16 out)
__global__ __launch_bounds__(256, 2) void qkv_gemm(
    const u16* __restrict__ xh, const u16* __restrict__ xl,
    const u16* __restrict__ wh, const u16* __restrict__ wl,
    const u16* __restrict__ wv,
    u16* __restrict__ qkh, u16* __restrict__ qkl, u16* __restrict__ vout) {
  __shared__ u16 Ah[128 * 32], Al[128 * 32], Bh[128 * 32], Bl[128 * 32];
  const int t = threadIdx.x, w = t >> 6, l = t & 63, g = l >> 4, lr = l & 15;
  const int m0 = blockIdx.y * 128, n0 = blockIdx.x * 128;
  const bool split = (n0 < 2048);
  const u16* bsrc_h = split ? (wh + (size_t)n0 * 1024) : (wv + (size_t)(n0 - 2048) * 1024);
  const u16* bsrc_l = split ? (wl + (size_t)n0 * 1024) : wl;
  const int wr = w >> 1, wc = w & 1;

  f32x4 zero = {0.f, 0.f, 0.f, 0.f};
  f32x4 acc[4][4];
#pragma unroll
  for (int mi = 0; mi < 4; ++mi)
#pragma unroll
    for (int ni = 0; ni < 4; ++ni) acc[mi][ni] = zero;

  for (int k0 = 0; k0 < 1024; k0 += 32) {
    __syncthreads();
#pragma unroll
    for (int i = 0; i < 2; ++i) {
      const int c = i * 256 + t;
      const int row = c >> 2;
      const int kc8 = (c & 3) * 8;
      const size_t goff = (size_t)row * 1024 + k0 + kc8;
      const int lo = i * 4096 + w * 1024;
      GLL(xh + (size_t)m0 * 1024 + goff, (char*)Ah + lo);
      GLL(bsrc_h + goff, (char*)Bh + lo);
      if (split) {
        GLL(xl + (size_t)m0 * 1024 + goff, (char*)Al + lo);
        GLL(bsrc_l + goff, (char*)Bl + lo);
      }
    }
    __syncthreads();

    bf16x8 ah[4], al[4];
#pragma unroll
    for (int mi = 0; mi < 4; ++mi) {
      const int idx = (wr * 64 + mi * 16 + lr) * 32 + g * 8;
      ah[mi] = *(const bf16x8*)&Ah[idx];
      if (split) al[mi] = *(const bf16x8*)&Al[idx];
    }
#pragma unroll
    for (int ni = 0; ni < 4; ++ni) {
      const int idx = (wc * 64 + ni * 16 + lr) * 32 + g * 8;
      bf16x8 bh = *(const bf16x8*)&Bh[idx];
      bf16x8 bl;
      if (split) bl = *(const bf16x8*)&Bl[idx];
#pragma unroll
      for (int mi = 0; mi < 4; ++mi) {
        acc[mi][ni] = __builtin_amdgcn_mfma_f32_16x16x32_bf16(ah[mi], bh, acc[mi][ni], 0, 0, 0);
        if (split) {
          acc[mi][ni] = __builtin_amdgcn_mfma_f32_16x16x32_bf16(al[mi], bh, acc[mi][ni], 0, 0, 0);
          acc[mi][ni] = __builtin_amdgcn_mfma_f32_16x16x32_bf16(ah[mi], bl, acc[mi][ni], 0, 0, 0);
        }
      }
    }
  }

#pragma unroll
  for (int mi = 0; mi < 4; ++mi)
#pragma unroll
    for (int ni = 0; ni < 4; ++ni)
#pragma unroll
      for (int r = 0; r < 4; ++r) {
        const int row = m0 + wr * 64 + mi * 16 + g * 4 + r;
        const int col = wc * 64 + ni * 16 + lr;
        const float cval = acc[mi][ni][r];
        if (split) {
          const u16 h = f2bf(cval);
          qkh[(size_t)row * 2048 + n0 + col] = h;
          qkl[(size_t)row * 2048 + n0 + col] = f2bf(cval - bf2f(h));
        } else {
          vout[(size_t)row * 1024 + (n0 - 2048) + col] = f2bf(cval);
        }
      }
}

// ---------------- flash attention with ALiBi ----------------
__global__ __launch_bounds__(256, 2) void attn(
    const u16* __restrict__ qkh, const u16* __restrict__ qkl,
    const u16* __restrict__ vbuf, u16* __restrict__ multi) {
  __shared__ u16 Ksh[64 * 64], Ksl[64 * 64], Vt[64 * 64];
  __shared__ u16 Ps[128 * 64];
  const int t = threadIdx.x, w = t >> 6, l = t & 63, g = l >> 4, lr = l & 15;
  const int qt = blockIdx.x, n = blockIdx.y, b = blockIdx.z;
  const int q0 = qt * 128;
  const size_t rowbase = (size_t)b * 2048;
  const u16* Qh = qkh + rowbase * 2048 + n * 64;
  const u16* Ql = qkl + rowbase * 2048 + n * 64;
  const u16* Kh = qkh + rowbase * 2048 + 1024 + n * 64;
  const u16* Kl = qkl + rowbase * 2048 + 1024 + n * 64;
  const u16* Vp = vbuf + rowbase * 1024 + n * 64;

  bf16x8 qfh[2][2], qfl[2][2];
#pragma unroll
  for (int mi = 0; mi < 2; ++mi)
#pragma unroll
    for (int kc = 0; kc < 2; ++kc) {
      const size_t off = (size_t)(q0 + w * 32 + mi * 16 + lr) * 2048 + kc * 32 + g * 8;
      qfh[mi][kc] = *(const bf16x8*)&Qh[off];
      qfl[mi][kc] = *(const bf16x8*)&Ql[off];
    }

  f32x4 zero = {0.f, 0.f, 0.f, 0.f};
  f32x4 o[2][4];
  float mst[2][4], lst[2][4];
#pragma unroll
  for (int mi = 0; mi < 2; ++mi) {
#pragma unroll
    for (int dn = 0; dn < 4; ++dn) o[mi][dn] = zero;
#pragma unroll
    for (int r = 0; r < 4; ++r) { mst[mi][r] = -3.0e38f; lst[mi][r] = 0.f; }
  }

  const float scale = 0.125f;
  const float slope = -(float)(n + 1);

  for (int kt = 0; kt < 2048; kt += 64) {
    __syncthreads();
    // stage K hi/lo: linear LDS dest, pre-swizzled global source (chunk j holds d-chunk j^(row&7))
#pragma unroll
    for (int i = 0; i < 2; ++i) {
      const int c = i * 256 + t;
      const int kr = c >> 3, j = c & 7;
      const int sj = j ^ (kr & 7);
      const size_t goff = (size_t)(kt + kr) * 2048 + sj * 8;
      const int lo = i * 4096 + w * 1024;
      GLL(Kh + goff, (char*)Ksh + lo);
      GLL(Kl + goff, (char*)Ksl + lo);
    }
    // stage V transposed (reg-staged), swizzled
#pragma unroll
    for (int i = 0; i < 2; ++i) {
      const int c = i * 256 + t;
      const int kr = c >> 3, dj = c & 7;
      bf16x8 vv = *(const bf16x8*)&Vp[(size_t)(kt + kr) * 1024 + dj * 8];
#pragma unroll
      for (int e = 0; e < 8; ++e) {
        const int d = dj * 8 + e;
        const int byte = d * 128 + ((((kr >> 3) ^ (d & 7)) << 4)) + ((kr & 7) * 2);
        *(u16*)((char*)Vt + byte) = (u16)vv[e];
      }
    }
    __syncthreads();

    // scores: 3-product split bf16
    f32x4 s[2][4];
#pragma unroll
    for (int mi = 0; mi < 2; ++mi)
#pragma unroll
      for (int ni = 0; ni < 4; ++ni) s[mi][ni] = zero;
#pragma unroll
    for (int ni = 0; ni < 4; ++ni) {
      bf16x8 bh[2], bl[2];
#pragma unroll
      for (int kc = 0; kc < 2; ++kc) {
        const int row = ni * 16 + lr;
        const int jd = kc * 4 + g;
        const int byte = row * 128 + ((jd ^ (row & 7)) << 4);
        bh[kc] = *(const bf16x8*)((const char*)Ksh + byte);
        bl[kc] = *(const bf16x8*)((const char*)Ksl + byte);
      }
#pragma unroll
      for (int mi = 0; mi < 2; ++mi) {
        f32x4 a = s[mi][ni];
        a = __builtin_amdgcn_mfma_f32_16x16x32_bf16(qfh[mi][0], bh[0], a, 0, 0, 0);
        a = __builtin_amdgcn_mfma_f32_16x16x32_bf16(qfh[mi][1], bh[1], a, 0, 0, 0);
        a = __builtin_amdgcn_mfma_f32_16x16x32_bf16(qfh[mi][0], bl[0], a, 0, 0, 0);
        a = __builtin_amdgcn_mfma_f32_16x16x32_bf16(qfh[mi][1], bl[1], a, 0, 0, 0);
        a = __builtin_amdgcn_mfma_f32_16x16x32_bf16(qfl[mi][0], bh[0], a, 0, 0, 0);
        a = __builtin_amdgcn_mfma_f32_16x16x32_bf16(qfl[mi][1], bh[1], a, 0, 0, 0);
        s[mi][ni] = a;
      }
    }

    // online softmax (per-wave rows; 16-lane butterfly over k-cols)
#pragma unroll
    for (int mi = 0; mi < 2; ++mi) {
      float rmax[4] = {-3.0e38f, -3.0e38f, -3.0e38f, -3.0e38f};
#pragma unroll
      for (int ni = 0; ni < 4; ++ni)
#pragma unroll
        for (int r = 0; r < 4; ++r) {
          const float kpos = (float)(kt + ni * 16 + lr);
          const float qpos = (float)(q0 + w * 32 + mi * 16 + g * 4 + r);
          const float v = s[mi][ni][r] * scale + slope * (kpos - qpos);
          s[mi][ni][r] = v;
          rmax[r] = fmaxf(rmax[r], v);
        }
#pragma unroll
      for (int r = 0; r < 4; ++r) {
        rmax[r] = fmaxf(rmax[r], __shfl_xor(rmax[r], 1));
        rmax[r] = fmaxf(rmax[r], __shfl_xor(rmax[r], 2));
        rmax[r] = fmaxf(rmax[r], __shfl_xor(rmax[r], 4));
        rmax[r] = fmaxf(rmax[r], __shfl_xor(rmax[r], 8));
      }
#pragma unroll
      for (int r = 0; r < 4; ++r) {
        const float mo = mst[mi][r];
        const float mn = fmaxf(mo, rmax[r]);
        const float alpha = __expf(mo - mn);
        mst[mi][r] = mn;
        lst[mi][r] *= alpha;
#pragma unroll
        for (int dn = 0; dn < 4; ++dn) o[mi][dn][r] *= alpha;
      }
      float rsum[4] = {0.f, 0.f, 0.f, 0.f};
#pragma unroll
      for (int ni = 0; ni < 4; ++ni)
#pragma unroll
        for (int r = 0; r < 4; ++r) {
          const float p = __expf(s[mi][ni][r] - mst[mi][r]);
          rsum[r] += p;
          const int prow = w * 32 + mi * 16 + g * 4 + r;
          const int col = ni * 16 + lr;
          const int byte = prow * 128 + ((((col >> 3) ^ (prow & 7)) << 4)) + ((col & 7) * 2);
          *(u16*)((char*)Ps + byte) = f2bf(p);
        }
#pragma unroll
      for (int r = 0; r < 4; ++r) {
        rsum[r] += __shfl_xor(rsum[r], 1);
        rsum[r] += __shfl_xor(rsum[r], 2);
        rsum[r] += __shfl_xor(rsum[r], 4);
        rsum[r] += __shfl_xor(rsum[r], 8);
        lst[mi][r] += rsum[r];
      }
    }

    // PV
    bf16x8 pa[2][2];
#pragma unroll
    for (int mi = 0; mi < 2; ++mi)
#pragma unroll
      for (int kc = 0; kc < 2; ++kc) {
        const int row = w * 32 + mi * 16 + lr;
        const int jk = kc * 4 + g;
        const int byte = row * 128 + ((jk ^ (row & 7)) << 4);
        pa[mi][kc] = *(const bf16x8*)((const char*)Ps + byte);
      }
#pragma unroll
    for (int dn = 0; dn < 4; ++dn) {
      bf16x8 vb[2];
#pragma unroll
      for (int kc = 0; kc < 2; ++kc) {
        const int row = dn * 16 + lr;
        const int jk = kc * 4 + g;
        const int byte = row * 128 + ((jk ^ (row & 7)) << 4);
        vb[kc] = *(const bf16x8*)((const char*)Vt + byte);
      }
#pragma unroll
      for (int mi = 0; mi < 2; ++mi) {
        o[mi][dn] = __builtin_amdgcn_mfma_f32_16x16x32_bf16(pa[mi][0], vb[0], o[mi][dn], 0, 0, 0);
        o[mi][dn] = __builtin_amdgcn_mfma_f32_16x16x32_bf16(pa[mi][1], vb[1], o[mi][dn], 0, 0, 0);
      }
    }
  }

#pragma unroll
  for (int mi = 0; mi < 2; ++mi)
#pragma unroll
    for (int dn = 0; dn < 4; ++dn)
#pragma unroll
      for (int r = 0; r < 4; ++r) {
        const float val = o[mi][dn][r] / lst[mi][r];
        const int qrow = q0 + w * 32 + mi * 16 + g * 4 + r;
        const int d = dn * 16 + lr;
        multi[(rowbase + qrow) * 1024 + n * 64 + d] = f2bf(val);
      }
}

// ---------------- output GEMM + bias ----------------
__global__ __launch_bounds__(256, 2) void out_gemm(
    const u16* __restrict__ A, const u16* __restrict__ Bw,
    const float* __restrict__ bias, float* __restrict__ out) {
  __shared__ u16 As[128 * 32], Bs[128 * 32];
  const int t = threadIdx.x, w = t >> 6, l = t & 63, g = l >> 4, lr = l & 15;
  const int m0 = blockIdx.y * 128, n0 = blockIdx.x * 128;
  const int wr = w >> 1, wc = w & 1;

  f32x4 zero = {0.f, 0.f, 0.f, 0.f};
  f32x4 acc[4][4];
#pragma unroll
  for (int mi = 0; mi < 4; ++mi)
#pragma unroll
    for (int ni = 0; ni < 4; ++ni) acc[mi][ni] = zero;

  for (int k0 = 0; k0 < 1024; k0 += 32) {
    __syncthreads();
#pragma unroll
    for (int i = 0; i < 2; ++i) {
      const int c = i * 256 + t;
      const int row = c >> 2;
      const int kc8 = (c & 3) * 8;
      const size_t goff = (size_t)row * 1024 + k0 + kc8;
      const int lo = i * 4096 + w * 1024;
      GLL(A + (size_t)m0 * 1024 + goff, (char*)As + lo);
      GLL(Bw + (size_t)n0 * 1024 + goff, (char*)Bs + lo);
    }
    __syncthreads();

    bf16x8 ah[4];
#pragma unroll
    for (int mi = 0; mi < 4; ++mi)
      ah[mi] = *(const bf16x8*)&As[(wr * 64 + mi * 16 + lr) * 32 + g * 8];
#pragma unroll
    for (int ni = 0; ni < 4; ++ni) {
      bf16x8 bh = *(const bf16x8*)&Bs[(wc * 64 + ni * 16 + lr) * 32 + g * 8];
#pragma unroll
      for (int mi = 0; mi < 4; ++mi)
        acc[mi][ni] = __builtin_amdgcn_mfma_f32_16x16x32_bf16(ah[mi], bh, acc[mi][ni], 0, 0, 0);
    }
  }

#pragma unroll
  for (int mi = 0; mi < 4; ++mi)
#pragma unroll
    for (int ni = 0; ni < 4; ++ni)
#pragma unroll
      for (int r = 0; r < 4; ++r) {
        const int row = m0 + wr * 64 + mi * 16 + g * 4 + r;
        const int col = n0 + wc * 64 + ni * 16 + lr;
        out[(size_t)row * 1024 + col] = acc[mi][ni][r] + bias[col];
      }
}

extern "C" void kernel_launch(void* const* d_in, const int* in_sizes, int n_in,
                              void* d_out, int out_size, void* d_ws, size_t ws_size,
                              hipStream_t stream) {
  (void)in_sizes; (void)n_in; (void)out_size; (void)ws_size;
  const float* x  = (const float*)d_in[0];
  const float* wq = (const float*)d_in[1];
  const float* wk = (const float*)d_in[2];
  const float* wv = (const float*)d_in[3];
  const float* wo = (const float*)d_in[4];
  const float* bo = (const float*)d_in[5];
  float* out = (float*)d_out;
  char* ws = (char*)d_ws;

  const size_t MB = 1024 * 1024;
  u16* xh   = (u16*)(ws + 0);        // 16 MB (reused as `multi` after QKV GEMM)
  u16* xl   = (u16*)(ws + 16 * MB);  // 16 MB
  u16* qkh  = (u16*)(ws + 32 * MB);  // 32 MB
  u16* qkl  = (u16*)(ws + 64 * MB);  // 32 MB
  u16* vbf  = (u16*)(ws + 96 * MB);  // 16 MB
  u16* wqkh = (u16*)(ws + 112 * MB); // 4 MB
  u16* wqkl = (u16*)(ws + 116 * MB); // 4 MB
  u16* wvb  = (u16*)(ws + 120 * MB); // 2 MB
  u16* wob  = (u16*)(ws + 122 * MB); // 2 MB
  u16* multi = xh;                   // alias: x dead after qkv_gemm

  prep_x<<<8192, 256, 0, stream>>>(x, xh, xl);
  prep_w<<<4096, 256, 0, stream>>>(wq, wk, wv, wo, wqkh, wqkl, wvb, wob);
  qkv_gemm<<<dim3(24, 64), 256, 0, stream>>>(xh, xl, wqkh, wqkl, wvb, qkh, qkl, vbf);
  attn<<<dim3(16, 16, 4), 256, 0, stream>>>(qkh, qkl, vbf, multi);
  out_gemm<<<dim3(8, 64), 256, 0, stream>>>(multi, wob, bo, out);
}